// Round 2
// baseline (2086.410 us; speedup 1.0000x reference)
//
#include <hip/hip_runtime.h>
#include <math.h>

typedef unsigned short u16;
typedef __attribute__((ext_vector_type(8))) __bf16 bf16x8;
typedef __attribute__((ext_vector_type(4))) float f32x4;

// ---------- bf16 helpers (bit-level, RNE) ----------
__device__ __forceinline__ float b2f(u16 u) {
    union { unsigned int u; float f; } a; a.u = ((unsigned int)u) << 16; return a.f;
}
__device__ __forceinline__ u16 f2b(float f) {
    union { float f; unsigned int u; } a; a.f = f;
    return (u16)((a.u + 0x7fffu + ((a.u >> 16) & 1u)) >> 16);
}

// window row -> spatial row (B=32, H=W=56, ws=7, 8x8 windows per image)
__device__ __forceinline__ int win2spatial(int r) {
    int wid = r / 49;
    int n   = r - wid * 49;
    int b   = wid >> 6;
    int wr  = wid & 63;
    int h   = (wr >> 3) * 7 + n / 7;
    int w   = (wr & 7) * 7 + n % 7;
    return (b * 56 + h) * 56 + w;
}

// ---------- fp32 -> bf16 conversion (weights) ----------
__global__ __launch_bounds__(256) void cvt_kernel(const float* __restrict__ in,
                                                  u16* __restrict__ out, int n)
{
    int i = (blockIdx.x * 256 + threadIdx.x) * 4;
    if (i < n) {
        float4 v = *reinterpret_cast<const float4*>(in + i);
        ushort4 o;
        o.x = f2b(v.x); o.y = f2b(v.y); o.z = f2b(v.z); o.w = f2b(v.w);
        *reinterpret_cast<ushort4*>(out + i) = o;
    }
}

// ---------- LayerNorm: read fp32 rows, write bf16 rows ----------
// REORDER=1: output row r comes from spatial row win2spatial(r) (window partition)
template<int REORDER>
__global__ __launch_bounds__(256) void ln_kernel(const float* __restrict__ inp,
                                                 const float* __restrict__ gw,
                                                 const float* __restrict__ bw,
                                                 u16* __restrict__ outp)
{
    int wave = threadIdx.x >> 6, lane = threadIdx.x & 63;
    int row  = blockIdx.x * 4 + wave;           // output row index
    int irow = REORDER ? win2spatial(row) : row;

    const float* p = inp + (size_t)irow * 256 + lane * 4;
    float4 x = *reinterpret_cast<const float4*>(p);
    float v[4] = {x.x, x.y, x.z, x.w};

    float s = v[0] + v[1] + v[2] + v[3];
    float q = v[0]*v[0] + v[1]*v[1] + v[2]*v[2] + v[3]*v[3];
#pragma unroll
    for (int off = 32; off > 0; off >>= 1) {
        s += __shfl_xor(s, off, 64);
        q += __shfl_xor(q, off, 64);
    }
    float mean = s * (1.0f / 256.0f);
    float var  = q * (1.0f / 256.0f) - mean * mean;
    float rstd = rsqrtf(var + 1e-5f);

    int c = lane * 4;
    ushort4 o;
    o.x = f2b((v[0] - mean) * rstd * gw[c + 0] + bw[c + 0]);
    o.y = f2b((v[1] - mean) * rstd * gw[c + 1] + bw[c + 1]);
    o.z = f2b((v[2] - mean) * rstd * gw[c + 2] + bw[c + 2]);
    o.w = f2b((v[3] - mean) * rstd * gw[c + 3] + bw[c + 3]);
    *reinterpret_cast<ushort4*>(outp + (size_t)row * 256 + c) = o;
}

// ---------- GEMM: C[M,N] = A[M,K](bf16) @ W[N,K](bf16)^T + bias(f32) ----------
// block = 256 threads (4 waves). Block tile 64(M) x 64(N); each wave 16x64.
// EPI 0: store bf16        EPI 1: exact GELU, store bf16
// EPI 2: proj -> x1_out[spatial] = resid[spatial] + val (fp32 store, scatter)
// EPI 3: out_f32[row] = resid[row] + val   (final output, fp32)
template<int EPI>
__global__ __launch_bounds__(256) void gemm_kernel(
    const u16* __restrict__ A, const u16* __restrict__ W,
    const float* __restrict__ bias,
    u16* __restrict__ out_b16,
    const float* __restrict__ resid,
    float* __restrict__ out_f32,
    int N, int K)
{
    int wave = threadIdx.x >> 6, lane = threadIdx.x & 63;
    int quad = lane >> 4, l16 = lane & 15;
    int m_base = blockIdx.x * 64 + wave * 16;
    int n_base = blockIdx.y * 64;
    int kv = K >> 3;   // row stride in bf16x8 units

    const bf16x8* Ap = reinterpret_cast<const bf16x8*>(A) + (size_t)(m_base + l16) * kv + quad;
    const bf16x8* B0 = reinterpret_cast<const bf16x8*>(W) + (size_t)(n_base + l16) * kv + quad;
    const bf16x8* B1 = B0 + (size_t)16 * kv;
    const bf16x8* B2 = B0 + (size_t)32 * kv;
    const bf16x8* B3 = B0 + (size_t)48 * kv;

    f32x4 acc[4];
#pragma unroll
    for (int t = 0; t < 4; ++t) acc[t] = (f32x4){0.f, 0.f, 0.f, 0.f};

    int ks = K >> 5;
    for (int kk = 0; kk < ks; ++kk) {
        bf16x8 a = Ap[(size_t)kk * 4];
        acc[0] = __builtin_amdgcn_mfma_f32_16x16x32_bf16(a, B0[(size_t)kk * 4], acc[0], 0, 0, 0);
        acc[1] = __builtin_amdgcn_mfma_f32_16x16x32_bf16(a, B1[(size_t)kk * 4], acc[1], 0, 0, 0);
        acc[2] = __builtin_amdgcn_mfma_f32_16x16x32_bf16(a, B2[(size_t)kk * 4], acc[2], 0, 0, 0);
        acc[3] = __builtin_amdgcn_mfma_f32_16x16x32_bf16(a, B3[(size_t)kk * 4], acc[3], 0, 0, 0);
    }

#pragma unroll
    for (int t = 0; t < 4; ++t) {
        int col = n_base + t * 16 + l16;
        float bv = bias[col];
#pragma unroll
        for (int r = 0; r < 4; ++r) {
            int row = m_base + quad * 4 + r;
            float val = acc[t][r] + bv;
            if (EPI == 0) {
                out_b16[(size_t)row * N + col] = f2b(val);
            } else if (EPI == 1) {
                float g = 0.5f * val * (1.0f + erff(val * 0.70710678118654752f));
                out_b16[(size_t)row * N + col] = f2b(g);
            } else if (EPI == 2) {
                int sr = win2spatial(row);
                size_t o = (size_t)sr * 256 + col;
                out_f32[o] = resid[o] + val;
            } else {
                size_t o = (size_t)row * N + col;
                out_f32[o] = resid[o] + val;
            }
        }
    }
}

// ---------- window attention ----------
// grid (2048 windows, 8 heads), block 256.
__global__ __launch_bounds__(256) void attn_kernel(const u16* __restrict__ qkv,
                                                   const float* __restrict__ btab,
                                                   u16* __restrict__ o)
{
    int wid = blockIdx.x, head = blockIdx.y;
    __shared__ float q[49][32];
    __shared__ float k[49][32];
    __shared__ float v[49][32];
    __shared__ float s[49][49];

    const size_t base = (size_t)wid * 49 * 768;
    const float scale = 0.17677669529663687f; // 32^-0.5
    for (int i = threadIdx.x; i < 49 * 32; i += 256) {
        int n = i >> 5, d = i & 31;
        size_t rb = base + (size_t)n * 768 + head * 32 + d;
        q[n][d] = b2f(qkv[rb]) * scale;
        k[n][d] = b2f(qkv[rb + 256]);
        v[n][d] = b2f(qkv[rb + 512]);
    }
    __syncthreads();

    for (int p = threadIdx.x; p < 49 * 49; p += 256) {
        int i = p / 49, j = p - (p / 49) * 49;
        float acc = 0.f;
#pragma unroll
        for (int d = 0; d < 32; ++d) acc += q[i][d] * k[j][d];
        int idx = (i / 7 - j / 7 + 6) * 13 + (i % 7 - j % 7 + 6);
        acc += btab[idx * 8 + head];
        s[i][j] = acc;
    }
    __syncthreads();

    if (threadIdx.x < 49) {
        int i = threadIdx.x;
        float mx = -1e30f;
        for (int j = 0; j < 49; ++j) mx = fmaxf(mx, s[i][j]);
        float sum = 0.f;
        for (int j = 0; j < 49; ++j) { float e = expf(s[i][j] - mx); s[i][j] = e; sum += e; }
        float inv = 1.0f / sum;
        for (int j = 0; j < 49; ++j) s[i][j] *= inv;
    }
    __syncthreads();

    for (int p = threadIdx.x; p < 49 * 32; p += 256) {
        int i = p >> 5, d = p & 31;
        float acc = 0.f;
        for (int j = 0; j < 49; ++j) acc += s[i][j] * v[j][d];
        o[((size_t)wid * 49 + i) * 256 + head * 32 + d] = f2b(acc);
    }
}

extern "C" void kernel_launch(void* const* d_in, const int* in_sizes, int n_in,
                              void* d_out, int out_size, void* d_ws, size_t ws_size,
                              hipStream_t stream)
{
    const float* x     = (const float*)d_in[0];
    const float* n1g   = (const float*)d_in[1];
    const float* n1b   = (const float*)d_in[2];
    const float* qkvw  = (const float*)d_in[3];
    const float* qkvb  = (const float*)d_in[4];
    const float* btab  = (const float*)d_in[5];
    const float* projw = (const float*)d_in[6];
    const float* projb = (const float*)d_in[7];
    const float* n2g   = (const float*)d_in[8];
    const float* n2b   = (const float*)d_in[9];
    const float* w1    = (const float*)d_in[10];
    const float* b1    = (const float*)d_in[11];
    const float* w2    = (const float*)d_in[12];
    const float* b2    = (const float*)d_in[13];

    char* ws  = (char*)d_ws;
    float* x1 = (float*)ws;                                   // 100352*256*4  = 102760448
    u16* bufA = (u16*)(ws + 102760448);                       // 100352*1024*2 = 205520896 (qkv, then ffn hidden)
    u16* bufB = (u16*)(ws + 102760448 + 205520896);           // 100352*256*2  =  51380224 (y, then o, then z)
    u16* wq   = (u16*)(ws + 102760448 + 205520896 + 51380224);// bf16 weights: qkv 196608 el
    u16* wp   = wq + 196608;                                  // proj 65536 el
    u16* wf1  = wp + 65536;                                   // ffn1 262144 el
    u16* wf2  = wf1 + 262144;                                 // ffn2 262144 el

    // 0. convert weights fp32 -> bf16
    cvt_kernel<<<192, 256, 0, stream>>>(qkvw, wq, 196608);
    cvt_kernel<<<64,  256, 0, stream>>>(projw, wp, 65536);
    cvt_kernel<<<256, 256, 0, stream>>>(w1, wf1, 262144);
    cvt_kernel<<<256, 256, 0, stream>>>(w2, wf2, 262144);

    // 1. LN1 + window partition (fp32 -> bf16, window-ordered)
    ln_kernel<1><<<25088, 256, 0, stream>>>(x, n1g, n1b, bufB);
    // 2. QKV GEMM: (100352x256) @ (768x256)^T -> bf16
    gemm_kernel<0><<<dim3(1568, 12), 256, 0, stream>>>(bufB, wq, qkvb, bufA,
                                                       nullptr, nullptr, 768, 256);
    // 3. window attention -> bf16 (window-ordered)
    attn_kernel<<<dim3(2048, 8), 256, 0, stream>>>(bufA, btab, bufB);
    // 4. proj GEMM + window reverse + residual -> x1 (fp32, spatial)
    gemm_kernel<2><<<dim3(1568, 4), 256, 0, stream>>>(bufB, wp, projb, nullptr,
                                                      x, x1, 256, 256);
    // 5. LN2 (fp32 -> bf16, spatial)
    ln_kernel<0><<<25088, 256, 0, stream>>>(x1, n2g, n2b, bufB);
    // 6. FFN1 + exact GELU -> bf16
    gemm_kernel<1><<<dim3(1568, 16), 256, 0, stream>>>(bufB, wf1, b1, bufA,
                                                       nullptr, nullptr, 1024, 256);
    // 7. FFN2 + residual -> d_out (fp32)
    gemm_kernel<3><<<dim3(1568, 4), 256, 0, stream>>>(bufA, wf2, b2, nullptr,
                                                      x1, (float*)d_out, 256, 1024);
}

// Round 3
// 1080.263 us; speedup vs baseline: 1.9314x; 1.9314x over previous
//
#include <hip/hip_runtime.h>
#include <math.h>

typedef unsigned short u16;
typedef __attribute__((ext_vector_type(8))) __bf16 bf16x8;
typedef __attribute__((ext_vector_type(4))) float f32x4;

// ---------- bf16 helpers (bit-level, RNE) ----------
__device__ __forceinline__ float b2f(u16 u) {
    union { unsigned int u; float f; } a; a.u = ((unsigned int)u) << 16; return a.f;
}
__device__ __forceinline__ u16 f2b(float f) {
    union { float f; unsigned int u; } a; a.f = f;
    return (u16)((a.u + 0x7fffu + ((a.u >> 16) & 1u)) >> 16);
}

// window row -> spatial row (B=32, H=W=56, ws=7, 8x8 windows per image)
__device__ __forceinline__ int win2spatial(int r) {
    int wid = r / 49;
    int n   = r - wid * 49;
    int b   = wid >> 6;
    int wr  = wid & 63;
    int h   = (wr >> 3) * 7 + n / 7;
    int w   = (wr & 7) * 7 + n % 7;
    return (b * 56 + h) * 56 + w;
}

// async global->LDS, 16B per lane. lds dest must be wave-uniform (HW adds lane*16).
__device__ __forceinline__ void stage16(const u16* g, u16* l) {
    __builtin_amdgcn_global_load_lds((const __attribute__((address_space(1))) void*)g,
                                     (__attribute__((address_space(3))) void*)l, 16, 0, 0);
}

// ---------- fp32 -> bf16 conversion (weights) ----------
__global__ __launch_bounds__(256) void cvt_kernel(const float* __restrict__ in,
                                                  u16* __restrict__ out, int n)
{
    int i = (blockIdx.x * 256 + threadIdx.x) * 4;
    if (i < n) {
        float4 v = *reinterpret_cast<const float4*>(in + i);
        ushort4 o;
        o.x = f2b(v.x); o.y = f2b(v.y); o.z = f2b(v.z); o.w = f2b(v.w);
        *reinterpret_cast<ushort4*>(out + i) = o;
    }
}

// ---------- LayerNorm: read fp32 rows, write bf16 rows ----------
template<int REORDER>
__global__ __launch_bounds__(256) void ln_kernel(const float* __restrict__ inp,
                                                 const float* __restrict__ gw,
                                                 const float* __restrict__ bw,
                                                 u16* __restrict__ outp)
{
    int wave = threadIdx.x >> 6, lane = threadIdx.x & 63;
    int row  = blockIdx.x * 4 + wave;
    int irow = REORDER ? win2spatial(row) : row;

    const float* p = inp + (size_t)irow * 256 + lane * 4;
    float4 x = *reinterpret_cast<const float4*>(p);
    float v[4] = {x.x, x.y, x.z, x.w};

    float s = v[0] + v[1] + v[2] + v[3];
    float q = v[0]*v[0] + v[1]*v[1] + v[2]*v[2] + v[3]*v[3];
#pragma unroll
    for (int off = 32; off > 0; off >>= 1) {
        s += __shfl_xor(s, off, 64);
        q += __shfl_xor(q, off, 64);
    }
    float mean = s * (1.0f / 256.0f);
    float var  = q * (1.0f / 256.0f) - mean * mean;
    float rstd = rsqrtf(var + 1e-5f);

    int c = lane * 4;
    ushort4 o;
    o.x = f2b((v[0] - mean) * rstd * gw[c + 0] + bw[c + 0]);
    o.y = f2b((v[1] - mean) * rstd * gw[c + 1] + bw[c + 1]);
    o.z = f2b((v[2] - mean) * rstd * gw[c + 2] + bw[c + 2]);
    o.w = f2b((v[3] - mean) * rstd * gw[c + 3] + bw[c + 3]);
    *reinterpret_cast<ushort4*>(outp + (size_t)row * 256 + c) = o;
}

// ---------- GEMM: C[M,N] = A[M,K](bf16) @ W[N,K](bf16)^T + bias(f32) ----------
// m97 structure: 128x128 block tile, BK=64, 4 waves each computing 64x64.
// LDS staged via global_load_lds width=16; XOR swizzle (kc ^ row&7) applied on
// the global-fetch side so ds_read_b128 fragment reads are 2-way (free).
// grid = (N/128, M/128): n fastest so A-tiles stay hot in L2 across N-columns.
// EPI 0: store bf16     EPI 1: exact GELU -> bf16
// EPI 2: out_f32[win2spatial(row)] = resid + val (proj + window-reverse + residual)
// EPI 3: out_f32[row] = resid[row] + val (final output)
template<int EPI>
__global__ __launch_bounds__(256) void gemm_kernel(
    const u16* __restrict__ A, const u16* __restrict__ W,
    const float* __restrict__ bias,
    u16* __restrict__ out_b16,
    const float* __restrict__ resid,
    float* __restrict__ out_f32,
    int N, int K)
{
    __shared__ u16 sA[1024 * 8];   // 128 rows x 8 chunks x 8 bf16 = 16 KB
    __shared__ u16 sB[1024 * 8];

    int t = threadIdx.x;
    int w = t >> 6, lane = t & 63;
    int quad = lane >> 4, l16 = lane & 15;
    int wm = (w >> 1) * 64, wn = (w & 1) * 64;

    int n_blk = blockIdx.x * 128;
    int m_blk = blockIdx.y * 128;

    // staging: thread t fetches row (g*32 + t>>3), col chunk (t&7)^((t>>3)&7)
    int srow = t >> 3;
    int scol = ((t & 7) ^ (srow & 7)) * 8;
    const u16* pA = A + (size_t)(m_blk + srow) * K + scol;
    const u16* pB = W + (size_t)(n_blk + srow) * K + scol;
    u16* lA = sA + w * 64 * 8;   // lane0 slot of wave w (call g adds g*256 slots)
    u16* lB = sB + w * 64 * 8;

    f32x4 acc[4][4];
#pragma unroll
    for (int i = 0; i < 4; ++i)
#pragma unroll
        for (int j = 0; j < 4; ++j) acc[i][j] = (f32x4){0.f, 0.f, 0.f, 0.f};

    for (int kb = 0; kb < K; kb += 64) {
        if (kb) __syncthreads();
#pragma unroll
        for (int g = 0; g < 4; ++g) {
            stage16(pA + (size_t)(g * 32) * K + kb, lA + g * 2048);
            stage16(pB + (size_t)(g * 32) * K + kb, lB + g * 2048);
        }
        __syncthreads();

#pragma unroll
        for (int q32 = 0; q32 < 2; ++q32) {
            bf16x8 af[4], bfr[4];
            int kc = q32 * 4 + quad;
#pragma unroll
            for (int tm = 0; tm < 4; ++tm) {
                int row = wm + tm * 16 + l16;
                af[tm] = *(const bf16x8*)(sA + (unsigned)(row * 8 + (kc ^ (row & 7))) * 8);
            }
#pragma unroll
            for (int tn = 0; tn < 4; ++tn) {
                int row = wn + tn * 16 + l16;
                bfr[tn] = *(const bf16x8*)(sB + (unsigned)(row * 8 + (kc ^ (row & 7))) * 8);
            }
#pragma unroll
            for (int tm = 0; tm < 4; ++tm)
#pragma unroll
                for (int tn = 0; tn < 4; ++tn)
                    acc[tm][tn] = __builtin_amdgcn_mfma_f32_16x16x32_bf16(af[tm], bfr[tn], acc[tm][tn], 0, 0, 0);
        }
    }

#pragma unroll
    for (int tn = 0; tn < 4; ++tn) {
        int col = n_blk + wn + tn * 16 + l16;
        float bv = bias[col];
#pragma unroll
        for (int tm = 0; tm < 4; ++tm) {
#pragma unroll
            for (int r = 0; r < 4; ++r) {
                int row = m_blk + wm + tm * 16 + quad * 4 + r;
                float val = acc[tm][tn][r] + bv;
                if (EPI == 0) {
                    out_b16[(size_t)row * N + col] = f2b(val);
                } else if (EPI == 1) {
                    float g = 0.5f * val * (1.0f + erff(val * 0.70710678118654752f));
                    out_b16[(size_t)row * N + col] = f2b(g);
                } else if (EPI == 2) {
                    int sr = win2spatial(row);
                    size_t o = (size_t)sr * 256 + col;
                    out_f32[o] = resid[o] + val;
                } else {
                    size_t o = (size_t)row * N + col;
                    out_f32[o] = resid[o] + val;
                }
            }
        }
    }
}

// ---------- window attention ----------
__global__ __launch_bounds__(256) void attn_kernel(const u16* __restrict__ qkv,
                                                   const float* __restrict__ btab,
                                                   u16* __restrict__ o)
{
    int wid = blockIdx.x, head = blockIdx.y;
    __shared__ float q[49][32];
    __shared__ float k[49][32];
    __shared__ float v[49][32];
    __shared__ float s[49][49];

    const size_t base = (size_t)wid * 49 * 768;
    const float scale = 0.17677669529663687f; // 32^-0.5
    for (int i = threadIdx.x; i < 49 * 32; i += 256) {
        int n = i >> 5, d = i & 31;
        size_t rb = base + (size_t)n * 768 + head * 32 + d;
        q[n][d] = b2f(qkv[rb]) * scale;
        k[n][d] = b2f(qkv[rb + 256]);
        v[n][d] = b2f(qkv[rb + 512]);
    }
    __syncthreads();

    for (int p = threadIdx.x; p < 49 * 49; p += 256) {
        int i = p / 49, j = p - (p / 49) * 49;
        float acc = 0.f;
#pragma unroll
        for (int d = 0; d < 32; ++d) acc += q[i][d] * k[j][d];
        int idx = (i / 7 - j / 7 + 6) * 13 + (i % 7 - j % 7 + 6);
        acc += btab[idx * 8 + head];
        s[i][j] = acc;
    }
    __syncthreads();

    if (threadIdx.x < 49) {
        int i = threadIdx.x;
        float mx = -1e30f;
        for (int j = 0; j < 49; ++j) mx = fmaxf(mx, s[i][j]);
        float sum = 0.f;
        for (int j = 0; j < 49; ++j) { float e = expf(s[i][j] - mx); s[i][j] = e; sum += e; }
        float inv = 1.0f / sum;
        for (int j = 0; j < 49; ++j) s[i][j] *= inv;
    }
    __syncthreads();

    for (int p = threadIdx.x; p < 49 * 32; p += 256) {
        int i = p >> 5, d = p & 31;
        float acc = 0.f;
        for (int j = 0; j < 49; ++j) acc += s[i][j] * v[j][d];
        o[((size_t)wid * 49 + i) * 256 + head * 32 + d] = f2b(acc);
    }
}

extern "C" void kernel_launch(void* const* d_in, const int* in_sizes, int n_in,
                              void* d_out, int out_size, void* d_ws, size_t ws_size,
                              hipStream_t stream)
{
    const float* x     = (const float*)d_in[0];
    const float* n1g   = (const float*)d_in[1];
    const float* n1b   = (const float*)d_in[2];
    const float* qkvw  = (const float*)d_in[3];
    const float* qkvb  = (const float*)d_in[4];
    const float* btab  = (const float*)d_in[5];
    const float* projw = (const float*)d_in[6];
    const float* projb = (const float*)d_in[7];
    const float* n2g   = (const float*)d_in[8];
    const float* n2b   = (const float*)d_in[9];
    const float* w1    = (const float*)d_in[10];
    const float* b1    = (const float*)d_in[11];
    const float* w2    = (const float*)d_in[12];
    const float* b2    = (const float*)d_in[13];

    char* ws  = (char*)d_ws;
    float* x1 = (float*)ws;                                   // 100352*256*4  = 102760448
    u16* bufA = (u16*)(ws + 102760448);                       // 100352*1024*2 = 205520896
    u16* bufB = (u16*)(ws + 102760448 + 205520896);           // 100352*256*2  =  51380224
    u16* wq   = (u16*)(ws + 102760448 + 205520896 + 51380224);// bf16 weights
    u16* wp   = wq + 196608;
    u16* wf1  = wp + 65536;
    u16* wf2  = wf1 + 262144;

    // 0. convert weights fp32 -> bf16
    cvt_kernel<<<192, 256, 0, stream>>>(qkvw, wq, 196608);
    cvt_kernel<<<64,  256, 0, stream>>>(projw, wp, 65536);
    cvt_kernel<<<256, 256, 0, stream>>>(w1, wf1, 262144);
    cvt_kernel<<<256, 256, 0, stream>>>(w2, wf2, 262144);

    // 1. LN1 + window partition (fp32 -> bf16, window-ordered)
    ln_kernel<1><<<25088, 256, 0, stream>>>(x, n1g, n1b, bufB);
    // 2. QKV GEMM: (100352x256) @ (768x256)^T -> bf16
    gemm_kernel<0><<<dim3(6, 784), 256, 0, stream>>>(bufB, wq, qkvb, bufA,
                                                     nullptr, nullptr, 768, 256);
    // 3. window attention -> bf16 (window-ordered)
    attn_kernel<<<dim3(2048, 8), 256, 0, stream>>>(bufA, btab, bufB);
    // 4. proj GEMM + window reverse + residual -> x1 (fp32, spatial)
    gemm_kernel<2><<<dim3(2, 784), 256, 0, stream>>>(bufB, wp, projb, nullptr,
                                                     x, x1, 256, 256);
    // 5. LN2 (fp32 -> bf16, spatial)
    ln_kernel<0><<<25088, 256, 0, stream>>>(x1, n2g, n2b, bufB);
    // 6. FFN1 + exact GELU -> bf16
    gemm_kernel<1><<<dim3(8, 784), 256, 0, stream>>>(bufB, wf1, b1, bufA,
                                                     nullptr, nullptr, 1024, 256);
    // 7. FFN2 + residual -> d_out (fp32)
    gemm_kernel<3><<<dim3(2, 784), 256, 0, stream>>>(bufA, wf2, b2, nullptr,
                                                     x1, (float*)d_out, 256, 1024);
}

// Round 4
// 732.474 us; speedup vs baseline: 2.8484x; 1.4748x over previous
//
#include <hip/hip_runtime.h>
#include <math.h>

typedef unsigned short u16;
typedef __attribute__((ext_vector_type(8))) __bf16 bf16x8;
typedef __attribute__((ext_vector_type(8))) u16 u16x8;
typedef __attribute__((ext_vector_type(4))) float f32x4;

// ---------- bf16 helpers (bit-level, RNE) ----------
__device__ __forceinline__ float b2f(u16 u) {
    union { unsigned int u; float f; } a; a.u = ((unsigned int)u) << 16; return a.f;
}
__device__ __forceinline__ u16 f2b(float f) {
    union { float f; unsigned int u; } a; a.f = f;
    return (u16)((a.u + 0x7fffu + ((a.u >> 16) & 1u)) >> 16);
}

// window row -> spatial row (B=32, H=W=56, ws=7, 8x8 windows per image)
__device__ __forceinline__ int win2spatial(int r) {
    int wid = r / 49;
    int n   = r - wid * 49;
    int b   = wid >> 6;
    int wr  = wid & 63;
    int h   = (wr >> 3) * 7 + n / 7;
    int w   = (wr & 7) * 7 + n % 7;
    return (b * 56 + h) * 56 + w;
}

// async global->LDS, 16B per lane. lds dest must be wave-uniform (HW adds lane*16).
__device__ __forceinline__ void stage16(const u16* g, u16* l) {
    __builtin_amdgcn_global_load_lds((const __attribute__((address_space(1))) void*)g,
                                     (__attribute__((address_space(3))) void*)l, 16, 0, 0);
}

// ---------- fp32 -> bf16 conversion (weights) ----------
__global__ __launch_bounds__(256) void cvt_kernel(const float* __restrict__ in,
                                                  u16* __restrict__ out, int n)
{
    int i = (blockIdx.x * 256 + threadIdx.x) * 4;
    if (i < n) {
        float4 v = *reinterpret_cast<const float4*>(in + i);
        ushort4 o;
        o.x = f2b(v.x); o.y = f2b(v.y); o.z = f2b(v.z); o.w = f2b(v.w);
        *reinterpret_cast<ushort4*>(out + i) = o;
    }
}

// ---------- bias tile prep: btile[head][64][64] fp32, -1e30 outside 49x49 ----------
__global__ __launch_bounds__(256) void bias_prep(const float* __restrict__ btab,
                                                 float* __restrict__ btile)
{
    int head = blockIdx.x;
    for (int idx = threadIdx.x; idx < 4096; idx += 256) {
        int i = idx >> 6, j = idx & 63;
        float v = -1e30f;
        if (i < 49 && j < 49) {
            int di = i / 7 - j / 7 + 6;
            int dj = i % 7 - j % 7 + 6;
            v = btab[(di * 13 + dj) * 8 + head];
        }
        btile[head * 4096 + idx] = v;
    }
}

// ---------- LayerNorm: read fp32 rows, write bf16 rows ----------
template<int REORDER>
__global__ __launch_bounds__(256) void ln_kernel(const float* __restrict__ inp,
                                                 const float* __restrict__ gw,
                                                 const float* __restrict__ bw,
                                                 u16* __restrict__ outp)
{
    int wave = threadIdx.x >> 6, lane = threadIdx.x & 63;
    int row  = blockIdx.x * 4 + wave;
    int irow = REORDER ? win2spatial(row) : row;

    const float* p = inp + (size_t)irow * 256 + lane * 4;
    float4 x = *reinterpret_cast<const float4*>(p);
    float v[4] = {x.x, x.y, x.z, x.w};

    float s = v[0] + v[1] + v[2] + v[3];
    float q = v[0]*v[0] + v[1]*v[1] + v[2]*v[2] + v[3]*v[3];
#pragma unroll
    for (int off = 32; off > 0; off >>= 1) {
        s += __shfl_xor(s, off, 64);
        q += __shfl_xor(q, off, 64);
    }
    float mean = s * (1.0f / 256.0f);
    float var  = q * (1.0f / 256.0f) - mean * mean;
    float rstd = rsqrtf(var + 1e-5f);

    int c = lane * 4;
    ushort4 o;
    o.x = f2b((v[0] - mean) * rstd * gw[c + 0] + bw[c + 0]);
    o.y = f2b((v[1] - mean) * rstd * gw[c + 1] + bw[c + 1]);
    o.z = f2b((v[2] - mean) * rstd * gw[c + 2] + bw[c + 2]);
    o.w = f2b((v[3] - mean) * rstd * gw[c + 3] + bw[c + 3]);
    *reinterpret_cast<ushort4*>(outp + (size_t)row * 256 + c) = o;
}

// ---------- GEMM (m97 structure, unchanged from round 3) ----------
template<int EPI>
__global__ __launch_bounds__(256) void gemm_kernel(
    const u16* __restrict__ A, const u16* __restrict__ W,
    const float* __restrict__ bias,
    u16* __restrict__ out_b16,
    const float* __restrict__ resid,
    float* __restrict__ out_f32,
    int N, int K)
{
    __shared__ u16 sA[1024 * 8];
    __shared__ u16 sB[1024 * 8];

    int t = threadIdx.x;
    int w = t >> 6, lane = t & 63;
    int quad = lane >> 4, l16 = lane & 15;
    int wm = (w >> 1) * 64, wn = (w & 1) * 64;

    int n_blk = blockIdx.x * 128;
    int m_blk = blockIdx.y * 128;

    int srow = t >> 3;
    int scol = ((t & 7) ^ (srow & 7)) * 8;
    const u16* pA = A + (size_t)(m_blk + srow) * K + scol;
    const u16* pB = W + (size_t)(n_blk + srow) * K + scol;
    u16* lA = sA + w * 64 * 8;
    u16* lB = sB + w * 64 * 8;

    f32x4 acc[4][4];
#pragma unroll
    for (int i = 0; i < 4; ++i)
#pragma unroll
        for (int j = 0; j < 4; ++j) acc[i][j] = (f32x4){0.f, 0.f, 0.f, 0.f};

    for (int kb = 0; kb < K; kb += 64) {
        if (kb) __syncthreads();
#pragma unroll
        for (int g = 0; g < 4; ++g) {
            stage16(pA + (size_t)(g * 32) * K + kb, lA + g * 2048);
            stage16(pB + (size_t)(g * 32) * K + kb, lB + g * 2048);
        }
        __syncthreads();

#pragma unroll
        for (int q32 = 0; q32 < 2; ++q32) {
            bf16x8 af[4], bfr[4];
            int kc = q32 * 4 + quad;
#pragma unroll
            for (int tm = 0; tm < 4; ++tm) {
                int row = wm + tm * 16 + l16;
                af[tm] = *(const bf16x8*)(sA + (unsigned)(row * 8 + (kc ^ (row & 7))) * 8);
            }
#pragma unroll
            for (int tn = 0; tn < 4; ++tn) {
                int row = wn + tn * 16 + l16;
                bfr[tn] = *(const bf16x8*)(sB + (unsigned)(row * 8 + (kc ^ (row & 7))) * 8);
            }
#pragma unroll
            for (int tm = 0; tm < 4; ++tm)
#pragma unroll
                for (int tn = 0; tn < 4; ++tn)
                    acc[tm][tn] = __builtin_amdgcn_mfma_f32_16x16x32_bf16(af[tm], bfr[tn], acc[tm][tn], 0, 0, 0);
        }
    }

#pragma unroll
    for (int tn = 0; tn < 4; ++tn) {
        int col = n_blk + wn + tn * 16 + l16;
        float bv = bias[col];
#pragma unroll
        for (int tm = 0; tm < 4; ++tm) {
#pragma unroll
            for (int r = 0; r < 4; ++r) {
                int row = m_blk + wm + tm * 16 + quad * 4 + r;
                float val = acc[tm][tn][r] + bv;
                if (EPI == 0) {
                    out_b16[(size_t)row * N + col] = f2b(val);
                } else if (EPI == 1) {
                    float g = 0.5f * val * (1.0f + erff(val * 0.70710678118654752f));
                    out_b16[(size_t)row * N + col] = f2b(g);
                } else if (EPI == 2) {
                    int sr = win2spatial(row);
                    size_t o = (size_t)sr * 256 + col;
                    out_f32[o] = resid[o] + val;
                } else {
                    size_t o = (size_t)row * N + col;
                    out_f32[o] = resid[o] + val;
                }
            }
        }
    }
}

// ---------- MFMA window attention ----------
// one wave per (window, head). QK^T: 64x64x32 (rows>=49 clamped, masked by bias
// tile). Softmax in C-regs. P -> LDS (bf16) -> A-frags; V transposed in LDS.
__global__ __launch_bounds__(64) void attn_kernel(const u16* __restrict__ qkv,
                                                  const float* __restrict__ btile,
                                                  u16* __restrict__ o)
{
    __shared__ u16 vT[32 * 72];   // V^T [d][j], stride 72 (16B-aligned rows)
    __shared__ u16 pl[64 * 72];   // P   [i][j]

    int wid = blockIdx.x, head = blockIdx.y;
    int lane = threadIdx.x;
    int quad = lane >> 4, l16 = lane & 15;

    const u16* wbase = qkv + (size_t)wid * 49 * 768;

    // zero vT (cols j>=49 must be 0.0 since junk there could be NaN)
    {
        unsigned long long* z = (unsigned long long*)vT;
        for (int i = lane; i < 576; i += 64) z[i] = 0ull;
    }

    // V transpose into LDS: lane = row j, iterate 4 chunks of 8 dims.
    // write instr i has uniform d across lanes -> banks = j/2 (conflict-free).
    if (lane < 49) {
#pragma unroll
        for (int c = 0; c < 4; ++c) {
            u16x8 vv = *(const u16x8*)(wbase + (size_t)lane * 768 + 512 + head * 32 + c * 8);
#pragma unroll
            for (int i = 0; i < 8; ++i) vT[(c * 8 + i) * 72 + lane] = vv[i];
        }
    }

    // QK^T fragments straight from global (16B per lane per tile)
    bf16x8 aq[4], bk[4];
#pragma unroll
    for (int t = 0; t < 4; ++t) {
        int r = t * 16 + l16; r = r > 48 ? 48 : r;
        aq[t] = *(const bf16x8*)(wbase + (size_t)r * 768 + head * 32 + quad * 8);
        bk[t] = *(const bf16x8*)(wbase + (size_t)r * 768 + 256 + head * 32 + quad * 8);
    }

    f32x4 s[4][4];
#pragma unroll
    for (int tm = 0; tm < 4; ++tm)
#pragma unroll
        for (int tn = 0; tn < 4; ++tn)
            s[tm][tn] = __builtin_amdgcn_mfma_f32_16x16x32_bf16(aq[tm], bk[tn],
                        (f32x4){0.f, 0.f, 0.f, 0.f}, 0, 0, 0);

    // scores = s*scale + bias ; bias tile has -1e30 masking for i/j >= 49
    const float scale = 0.17677669529663687f;
    const float* bt = btile + head * 4096;
#pragma unroll
    for (int tm = 0; tm < 4; ++tm)
#pragma unroll
        for (int tn = 0; tn < 4; ++tn)
#pragma unroll
            for (int r = 0; r < 4; ++r) {
                float b = bt[(tm * 16 + quad * 4 + r) * 64 + tn * 16 + l16];
                s[tm][tn][r] = s[tm][tn][r] * scale + b;
            }

    // softmax over cols (4 tn regs x 16 lanes), rows = (tm, quad, r)
#pragma unroll
    for (int tm = 0; tm < 4; ++tm)
#pragma unroll
        for (int r = 0; r < 4; ++r) {
            float mx = fmaxf(fmaxf(s[tm][0][r], s[tm][1][r]), fmaxf(s[tm][2][r], s[tm][3][r]));
#pragma unroll
            for (int off = 1; off < 16; off <<= 1) mx = fmaxf(mx, __shfl_xor(mx, off, 64));
            float sum = 0.f;
#pragma unroll
            for (int tn = 0; tn < 4; ++tn) {
                float e = __expf(s[tm][tn][r] - mx);
                s[tm][tn][r] = e; sum += e;
            }
#pragma unroll
            for (int off = 1; off < 16; off <<= 1) sum += __shfl_xor(sum, off, 64);
            float inv = 1.0f / sum;
#pragma unroll
            for (int tn = 0; tn < 4; ++tn) s[tm][tn][r] *= inv;
        }

    __syncthreads();
    // store P (bf16) row-major [query][key]
#pragma unroll
    for (int tm = 0; tm < 4; ++tm)
#pragma unroll
        for (int tn = 0; tn < 4; ++tn)
#pragma unroll
            for (int r = 0; r < 4; ++r)
                pl[(tm * 16 + quad * 4 + r) * 72 + tn * 16 + l16] = f2b(s[tm][tn][r]);
    __syncthreads();

    // PV: M=64, N=32, K=64
    f32x4 oa[4][2];
#pragma unroll
    for (int tm = 0; tm < 4; ++tm)
#pragma unroll
        for (int tn = 0; tn < 2; ++tn) oa[tm][tn] = (f32x4){0.f, 0.f, 0.f, 0.f};

#pragma unroll
    for (int ks = 0; ks < 2; ++ks) {
        bf16x8 pa[4], vb[2];
#pragma unroll
        for (int tm = 0; tm < 4; ++tm)
            pa[tm] = *(const bf16x8*)(pl + (unsigned)(tm * 16 + l16) * 72 + ks * 32 + quad * 8);
#pragma unroll
        for (int tn = 0; tn < 2; ++tn)
            vb[tn] = *(const bf16x8*)(vT + (unsigned)(tn * 16 + l16) * 72 + ks * 32 + quad * 8);
#pragma unroll
        for (int tm = 0; tm < 4; ++tm)
#pragma unroll
            for (int tn = 0; tn < 2; ++tn)
                oa[tm][tn] = __builtin_amdgcn_mfma_f32_16x16x32_bf16(pa[tm], vb[tn], oa[tm][tn], 0, 0, 0);
    }

    // store O rows < 49
    u16* ob = o + (size_t)wid * 49 * 256 + head * 32;
#pragma unroll
    for (int tm = 0; tm < 4; ++tm)
#pragma unroll
        for (int r = 0; r < 4; ++r) {
            int m = tm * 16 + quad * 4 + r;
            if (m < 49) {
#pragma unroll
                for (int tn = 0; tn < 2; ++tn)
                    ob[(size_t)m * 256 + tn * 16 + l16] = f2b(oa[tm][tn][r]);
            }
        }
}

extern "C" void kernel_launch(void* const* d_in, const int* in_sizes, int n_in,
                              void* d_out, int out_size, void* d_ws, size_t ws_size,
                              hipStream_t stream)
{
    const float* x     = (const float*)d_in[0];
    const float* n1g   = (const float*)d_in[1];
    const float* n1b   = (const float*)d_in[2];
    const float* qkvw  = (const float*)d_in[3];
    const float* qkvb  = (const float*)d_in[4];
    const float* btab  = (const float*)d_in[5];
    const float* projw = (const float*)d_in[6];
    const float* projb = (const float*)d_in[7];
    const float* n2g   = (const float*)d_in[8];
    const float* n2b   = (const float*)d_in[9];
    const float* w1    = (const float*)d_in[10];
    const float* b1    = (const float*)d_in[11];
    const float* w2    = (const float*)d_in[12];
    const float* b2    = (const float*)d_in[13];

    char* ws  = (char*)d_ws;
    float* x1 = (float*)ws;                                   // 100352*256*4  = 102760448
    u16* bufA = (u16*)(ws + 102760448);                       // 100352*1024*2 = 205520896
    u16* bufB = (u16*)(ws + 102760448 + 205520896);           // 100352*256*2  =  51380224
    u16* wq   = (u16*)(ws + 102760448 + 205520896 + 51380224);// bf16 weights
    u16* wp   = wq + 196608;
    u16* wf1  = wp + 65536;
    u16* wf2  = wf1 + 262144;
    // bias tile lives in the unused tail of bufA during attention
    // (qkv uses 100352*768 el of bufA; tail is free until FFN1)
    float* btile = (float*)(ws + 102760448 + 154140672);      // 8*64*64 fp32 = 131072 B

    // 0. convert weights fp32 -> bf16 ; build bias tile
    cvt_kernel<<<192, 256, 0, stream>>>(qkvw, wq, 196608);
    cvt_kernel<<<64,  256, 0, stream>>>(projw, wp, 65536);
    cvt_kernel<<<256, 256, 0, stream>>>(w1, wf1, 262144);
    cvt_kernel<<<256, 256, 0, stream>>>(w2, wf2, 262144);
    bias_prep<<<8, 256, 0, stream>>>(btab, btile);

    // 1. LN1 + window partition (fp32 -> bf16, window-ordered)
    ln_kernel<1><<<25088, 256, 0, stream>>>(x, n1g, n1b, bufB);
    // 2. QKV GEMM: (100352x256) @ (768x256)^T -> bf16
    gemm_kernel<0><<<dim3(6, 784), 256, 0, stream>>>(bufB, wq, qkvb, bufA,
                                                     nullptr, nullptr, 768, 256);
    // 3. MFMA window attention -> bf16 (window-ordered)
    attn_kernel<<<dim3(2048, 8), 64, 0, stream>>>(bufA, btile, bufB);
    // 4. proj GEMM + window reverse + residual -> x1 (fp32, spatial)
    gemm_kernel<2><<<dim3(2, 784), 256, 0, stream>>>(bufB, wp, projb, nullptr,
                                                     x, x1, 256, 256);
    // 5. LN2 (fp32 -> bf16, spatial)
    ln_kernel<0><<<25088, 256, 0, stream>>>(x1, n2g, n2b, bufB);
    // 6. FFN1 + exact GELU -> bf16
    gemm_kernel<1><<<dim3(8, 784), 256, 0, stream>>>(bufB, wf1, b1, bufA,
                                                     nullptr, nullptr, 1024, 256);
    // 7. FFN2 + residual -> d_out (fp32)
    gemm_kernel<3><<<dim3(2, 784), 256, 0, stream>>>(bufA, wf2, b2, nullptr,
                                                     x1, (float*)d_out, 256, 1024);
}

// Round 5
// 706.566 us; speedup vs baseline: 2.9529x; 1.0367x over previous
//
#include <hip/hip_runtime.h>
#include <math.h>

typedef unsigned short u16;
typedef __attribute__((ext_vector_type(8))) __bf16 bf16x8;
typedef __attribute__((ext_vector_type(8))) u16 u16x8;
typedef __attribute__((ext_vector_type(4))) float f32x4;

// ---------- bf16 helpers (bit-level, RNE) ----------
__device__ __forceinline__ float b2f(u16 u) {
    union { unsigned int u; float f; } a; a.u = ((unsigned int)u) << 16; return a.f;
}
__device__ __forceinline__ u16 f2b(float f) {
    union { float f; unsigned int u; } a; a.f = f;
    return (u16)((a.u + 0x7fffu + ((a.u >> 16) & 1u)) >> 16);
}

// tanh-form GELU (max ~1.5e-3 abs dev from exact; threshold budget 0.114)
__device__ __forceinline__ float gelu_t(float x) {
    float u = 1.5957691216057308f * (x + 0.044715f * x * x * x); // 2*sqrt(2/pi)*(..)
    float e = __expf(u);
    float t = (e - 1.0f) / (e + 1.0f);
    return 0.5f * x * (1.0f + t);
}

// window row -> spatial row (B=32, H=W=56, ws=7, 8x8 windows per image)
__device__ __forceinline__ int win2spatial(int r) {
    int wid = r / 49;
    int n   = r - wid * 49;
    int b   = wid >> 6;
    int wr  = wid & 63;
    int h   = (wr >> 3) * 7 + n / 7;
    int w   = (wr & 7) * 7 + n % 7;
    return (b * 56 + h) * 56 + w;
}

// async global->LDS, 16B per lane. lds dest must be wave-uniform (HW adds lane*16).
__device__ __forceinline__ void stage16(const u16* g, u16* l) {
    __builtin_amdgcn_global_load_lds((const __attribute__((address_space(1))) void*)g,
                                     (__attribute__((address_space(3))) void*)l, 16, 0, 0);
}

// ---------- fp32 -> bf16 conversion (weights) ----------
__global__ __launch_bounds__(256) void cvt_kernel(const float* __restrict__ in,
                                                  u16* __restrict__ out, int n)
{
    int i = (blockIdx.x * 256 + threadIdx.x) * 4;
    if (i < n) {
        float4 v = *reinterpret_cast<const float4*>(in + i);
        ushort4 o;
        o.x = f2b(v.x); o.y = f2b(v.y); o.z = f2b(v.z); o.w = f2b(v.w);
        *reinterpret_cast<ushort4*>(out + i) = o;
    }
}

// ---------- bias tile prep: btile[head][64][64] fp32, -1e30 outside 49x49 ----------
__global__ __launch_bounds__(256) void bias_prep(const float* __restrict__ btab,
                                                 float* __restrict__ btile)
{
    int head = blockIdx.x;
    for (int idx = threadIdx.x; idx < 4096; idx += 256) {
        int i = idx >> 6, j = idx & 63;
        float v = -1e30f;
        if (i < 49 && j < 49) {
            int di = i / 7 - j / 7 + 6;
            int dj = i % 7 - j % 7 + 6;
            v = btab[(di * 13 + dj) * 8 + head];
        }
        btile[head * 4096 + idx] = v;
    }
}

// ---------- LayerNorm: read fp32/bf16 rows, write bf16 rows ----------
// REORDER=1: output row r comes from spatial row win2spatial(r)
template<int REORDER, int INBF>
__global__ __launch_bounds__(256) void ln_kernel(const void* __restrict__ inp,
                                                 const float* __restrict__ gw,
                                                 const float* __restrict__ bw,
                                                 u16* __restrict__ outp)
{
    int wave = threadIdx.x >> 6, lane = threadIdx.x & 63;
    int row  = blockIdx.x * 4 + wave;
    int irow = REORDER ? win2spatial(row) : row;

    float v[4];
    if (INBF) {
        ushort4 xx = *reinterpret_cast<const ushort4*>((const u16*)inp + (size_t)irow * 256 + lane * 4);
        v[0] = b2f(xx.x); v[1] = b2f(xx.y); v[2] = b2f(xx.z); v[3] = b2f(xx.w);
    } else {
        float4 xx = *reinterpret_cast<const float4*>((const float*)inp + (size_t)irow * 256 + lane * 4);
        v[0] = xx.x; v[1] = xx.y; v[2] = xx.z; v[3] = xx.w;
    }

    float s = v[0] + v[1] + v[2] + v[3];
    float q = v[0]*v[0] + v[1]*v[1] + v[2]*v[2] + v[3]*v[3];
#pragma unroll
    for (int off = 32; off > 0; off >>= 1) {
        s += __shfl_xor(s, off, 64);
        q += __shfl_xor(q, off, 64);
    }
    float mean = s * (1.0f / 256.0f);
    float var  = q * (1.0f / 256.0f) - mean * mean;
    float rstd = rsqrtf(var + 1e-5f);

    int c = lane * 4;
    ushort4 o;
    o.x = f2b((v[0] - mean) * rstd * gw[c + 0] + bw[c + 0]);
    o.y = f2b((v[1] - mean) * rstd * gw[c + 1] + bw[c + 1]);
    o.z = f2b((v[2] - mean) * rstd * gw[c + 2] + bw[c + 2]);
    o.w = f2b((v[3] - mean) * rstd * gw[c + 3] + bw[c + 3]);
    *reinterpret_cast<ushort4*>(outp + (size_t)row * 256 + c) = o;
}

// ---------- GEMM: C[M,N] = A[M,K](bf16) @ W[N,K](bf16)^T + bias(f32) ----------
// 128x128 tile, BK=64, 4 waves x 64x64. global_load_lds staging, XOR-swizzled.
// 1D grid with XCD swizzle: all n-blocks of an m-tile land on one XCD (L2 reuse).
// EPI 0: bf16 C via LDS-transpose -> dwordx4 stores
// EPI 1: tanh-GELU, bf16 C via transpose
// EPI 2: x1[win2spatial(row)] = bf16(residF[spatial] + val), via transpose
// EPI 3: outF[row] = b2f(residU[row]) + val  (fp32 direct, 64B/quad stores)
template<int EPI>
__global__ __launch_bounds__(256) void gemm_kernel(
    const u16* __restrict__ A, const u16* __restrict__ W,
    const float* __restrict__ bias,
    u16* __restrict__ outU, float* __restrict__ outF,
    const float* __restrict__ residF, const u16* __restrict__ residU,
    int N, int K, int nB)
{
    __shared__ char smem[40960];
    u16* sA = (u16*)smem;            // 16 KB
    u16* sB = (u16*)(smem + 16384);  // 16 KB

    int t = threadIdx.x;
    int w = t >> 6, lane = t & 63;
    int quad = lane >> 4, l16 = lane & 15;
    int wm = (w >> 1) * 64, wn = (w & 1) * 64;

    // XCD-aware swizzle: b%8 = XCD; within an XCD, iterate n fastest.
    int b = blockIdx.x;
    int xcd = b & 7, g = b >> 3;
    int n_i = g % nB;
    int m_i = (g / nB) * 8 + xcd;
    int n_blk = n_i * 128, m_blk = m_i * 128;

    int srow = t >> 3;
    int scol = ((t & 7) ^ (srow & 7)) * 8;
    const u16* pA = A + (size_t)(m_blk + srow) * K + scol;
    const u16* pB = W + (size_t)(n_blk + srow) * K + scol;
    u16* lA = sA + w * 64 * 8;
    u16* lB = sB + w * 64 * 8;

    f32x4 acc[4][4];
#pragma unroll
    for (int i = 0; i < 4; ++i)
#pragma unroll
        for (int j = 0; j < 4; ++j) acc[i][j] = (f32x4){0.f, 0.f, 0.f, 0.f};

    for (int kb = 0; kb < K; kb += 64) {
        if (kb) __syncthreads();
#pragma unroll
        for (int gg = 0; gg < 4; ++gg) {
            stage16(pA + (size_t)(gg * 32) * K + kb, lA + gg * 2048);
            stage16(pB + (size_t)(gg * 32) * K + kb, lB + gg * 2048);
        }
        __syncthreads();

#pragma unroll
        for (int q32 = 0; q32 < 2; ++q32) {
            bf16x8 af[4], bfr[4];
            int kc = q32 * 4 + quad;
#pragma unroll
            for (int tm = 0; tm < 4; ++tm) {
                int row = wm + tm * 16 + l16;
                af[tm] = *(const bf16x8*)(sA + (unsigned)(row * 8 + (kc ^ (row & 7))) * 8);
            }
#pragma unroll
            for (int tn = 0; tn < 4; ++tn) {
                int row = wn + tn * 16 + l16;
                bfr[tn] = *(const bf16x8*)(sB + (unsigned)(row * 8 + (kc ^ (row & 7))) * 8);
            }
#pragma unroll
            for (int tm = 0; tm < 4; ++tm)
#pragma unroll
                for (int tn = 0; tn < 4; ++tn)
                    acc[tm][tn] = __builtin_amdgcn_mfma_f32_16x16x32_bf16(af[tm], bfr[tn], acc[tm][tn], 0, 0, 0);
        }
    }

    if (EPI == 3) {
        // fp32 direct stores: 16 lanes x 4B = 64B contiguous per quad (full granule)
#pragma unroll
        for (int tn = 0; tn < 4; ++tn) {
            int col = n_blk + wn + tn * 16 + l16;
            float bv = bias[col];
#pragma unroll
            for (int tm = 0; tm < 4; ++tm)
#pragma unroll
                for (int r = 0; r < 4; ++r) {
                    int row = m_blk + wm + tm * 16 + quad * 4 + r;
                    size_t o = (size_t)row * N + col;
                    outF[o] = b2f(residU[o]) + acc[tm][tn][r] + bv;
                }
        }
        return;
    }

    // bf16 epilogues: transpose via wave-private LDS (stride 80 u16 rows)
    __syncthreads();   // all waves done with sA/sB
    u16* tp = (u16*)smem + w * 5120;   // 10240 B per wave

#pragma unroll
    for (int tn = 0; tn < 4; ++tn) {
        int colL = tn * 16 + l16;
        float bv = bias[n_blk + wn + colL];
#pragma unroll
        for (int tm = 0; tm < 4; ++tm)
#pragma unroll
            for (int r = 0; r < 4; ++r) {
                int rowL = tm * 16 + quad * 4 + r;
                float val = acc[tm][tn][r] + bv;
                if (EPI == 1) val = gelu_t(val);
                if (EPI == 2) {
                    int sr = win2spatial(m_blk + wm + rowL);
                    val += residF[(size_t)sr * 256 + n_blk + wn + colL];
                }
                tp[rowL * 80 + colL] = f2b(val);
            }
    }
    // wave-private region: compiler inserts lgkmcnt wait on the dependency
#pragma unroll
    for (int it = 0; it < 8; ++it) {
        int rowL = it * 8 + (lane >> 3);
        int chunk = (lane & 7) * 8;
        u16x8 vv = *(const u16x8*)(tp + rowL * 80 + chunk);
        int grow = m_blk + wm + rowL;
        if (EPI == 2) {
            *(u16x8*)(outU + (size_t)win2spatial(grow) * 256 + n_blk + wn + chunk) = vv;
        } else {
            *(u16x8*)(outU + (size_t)grow * N + n_blk + wn + chunk) = vv;
        }
    }
}

// ---------- MFMA window attention (unchanged from round 4) ----------
__global__ __launch_bounds__(64) void attn_kernel(const u16* __restrict__ qkv,
                                                  const float* __restrict__ btile,
                                                  u16* __restrict__ o)
{
    __shared__ u16 vT[32 * 72];
    __shared__ u16 pl[64 * 72];

    int wid = blockIdx.x, head = blockIdx.y;
    int lane = threadIdx.x;
    int quad = lane >> 4, l16 = lane & 15;

    const u16* wbase = qkv + (size_t)wid * 49 * 768;

    {
        unsigned long long* z = (unsigned long long*)vT;
        for (int i = lane; i < 576; i += 64) z[i] = 0ull;
    }

    if (lane < 49) {
#pragma unroll
        for (int c = 0; c < 4; ++c) {
            u16x8 vv = *(const u16x8*)(wbase + (size_t)lane * 768 + 512 + head * 32 + c * 8);
#pragma unroll
            for (int i = 0; i < 8; ++i) vT[(c * 8 + i) * 72 + lane] = vv[i];
        }
    }

    bf16x8 aq[4], bk[4];
#pragma unroll
    for (int t = 0; t < 4; ++t) {
        int r = t * 16 + l16; r = r > 48 ? 48 : r;
        aq[t] = *(const bf16x8*)(wbase + (size_t)r * 768 + head * 32 + quad * 8);
        bk[t] = *(const bf16x8*)(wbase + (size_t)r * 768 + 256 + head * 32 + quad * 8);
    }

    f32x4 s[4][4];
#pragma unroll
    for (int tm = 0; tm < 4; ++tm)
#pragma unroll
        for (int tn = 0; tn < 4; ++tn)
            s[tm][tn] = __builtin_amdgcn_mfma_f32_16x16x32_bf16(aq[tm], bk[tn],
                        (f32x4){0.f, 0.f, 0.f, 0.f}, 0, 0, 0);

    const float scale = 0.17677669529663687f;
    const float* bt = btile + head * 4096;
#pragma unroll
    for (int tm = 0; tm < 4; ++tm)
#pragma unroll
        for (int tn = 0; tn < 4; ++tn)
#pragma unroll
            for (int r = 0; r < 4; ++r) {
                float bb = bt[(tm * 16 + quad * 4 + r) * 64 + tn * 16 + l16];
                s[tm][tn][r] = s[tm][tn][r] * scale + bb;
            }

#pragma unroll
    for (int tm = 0; tm < 4; ++tm)
#pragma unroll
        for (int r = 0; r < 4; ++r) {
            float mx = fmaxf(fmaxf(s[tm][0][r], s[tm][1][r]), fmaxf(s[tm][2][r], s[tm][3][r]));
#pragma unroll
            for (int off = 1; off < 16; off <<= 1) mx = fmaxf(mx, __shfl_xor(mx, off, 64));
            float sum = 0.f;
#pragma unroll
            for (int tn = 0; tn < 4; ++tn) {
                float e = __expf(s[tm][tn][r] - mx);
                s[tm][tn][r] = e; sum += e;
            }
#pragma unroll
            for (int off = 1; off < 16; off <<= 1) sum += __shfl_xor(sum, off, 64);
            float inv = 1.0f / sum;
#pragma unroll
            for (int tn = 0; tn < 4; ++tn) s[tm][tn][r] *= inv;
        }

    __syncthreads();
#pragma unroll
    for (int tm = 0; tm < 4; ++tm)
#pragma unroll
        for (int tn = 0; tn < 4; ++tn)
#pragma unroll
            for (int r = 0; r < 4; ++r)
                pl[(tm * 16 + quad * 4 + r) * 72 + tn * 16 + l16] = f2b(s[tm][tn][r]);
    __syncthreads();

    f32x4 oa[4][2];
#pragma unroll
    for (int tm = 0; tm < 4; ++tm)
#pragma unroll
        for (int tn = 0; tn < 2; ++tn) oa[tm][tn] = (f32x4){0.f, 0.f, 0.f, 0.f};

#pragma unroll
    for (int ks = 0; ks < 2; ++ks) {
        bf16x8 pa[4], vb[2];
#pragma unroll
        for (int tm = 0; tm < 4; ++tm)
            pa[tm] = *(const bf16x8*)(pl + (unsigned)(tm * 16 + l16) * 72 + ks * 32 + quad * 8);
#pragma unroll
        for (int tn = 0; tn < 2; ++tn)
            vb[tn] = *(const bf16x8*)(vT + (unsigned)(tn * 16 + l16) * 72 + ks * 32 + quad * 8);
#pragma unroll
        for (int tm = 0; tm < 4; ++tm)
#pragma unroll
            for (int tn = 0; tn < 2; ++tn)
                oa[tm][tn] = __builtin_amdgcn_mfma_f32_16x16x32_bf16(pa[tm], vb[tn], oa[tm][tn], 0, 0, 0);
    }

    u16* ob = o + (size_t)wid * 49 * 256 + head * 32;
#pragma unroll
    for (int tm = 0; tm < 4; ++tm)
#pragma unroll
        for (int r = 0; r < 4; ++r) {
            int m = tm * 16 + quad * 4 + r;
            if (m < 49) {
#pragma unroll
                for (int tn = 0; tn < 2; ++tn)
                    ob[(size_t)m * 256 + tn * 16 + l16] = f2b(oa[tm][tn][r]);
            }
        }
}

extern "C" void kernel_launch(void* const* d_in, const int* in_sizes, int n_in,
                              void* d_out, int out_size, void* d_ws, size_t ws_size,
                              hipStream_t stream)
{
    const float* x     = (const float*)d_in[0];
    const float* n1g   = (const float*)d_in[1];
    const float* n1b   = (const float*)d_in[2];
    const float* qkvw  = (const float*)d_in[3];
    const float* qkvb  = (const float*)d_in[4];
    const float* btab  = (const float*)d_in[5];
    const float* projw = (const float*)d_in[6];
    const float* projb = (const float*)d_in[7];
    const float* n2g   = (const float*)d_in[8];
    const float* n2b   = (const float*)d_in[9];
    const float* w1    = (const float*)d_in[10];
    const float* b1    = (const float*)d_in[11];
    const float* w2    = (const float*)d_in[12];
    const float* b2    = (const float*)d_in[13];

    char* ws  = (char*)d_ws;
    u16* x1   = (u16*)ws;                                     // bf16 residual stream, 51 MB (102 MB reserved)
    u16* bufA = (u16*)(ws + 102760448);                       // 100352*1024*2 = 205520896
    u16* bufB = (u16*)(ws + 102760448 + 205520896);           // 100352*256*2  =  51380224
    u16* wq   = (u16*)(ws + 102760448 + 205520896 + 51380224);// bf16 weights
    u16* wp   = wq + 196608;
    u16* wf1  = wp + 65536;
    u16* wf2  = wf1 + 262144;
    float* btile = (float*)(ws + 102760448 + 154140672);      // 8*64*64 fp32, tail of bufA until FFN1

    // 0. weights fp32->bf16, bias tile
    cvt_kernel<<<192, 256, 0, stream>>>(qkvw, wq, 196608);
    cvt_kernel<<<64,  256, 0, stream>>>(projw, wp, 65536);
    cvt_kernel<<<256, 256, 0, stream>>>(w1, wf1, 262144);
    cvt_kernel<<<256, 256, 0, stream>>>(w2, wf2, 262144);
    bias_prep<<<8, 256, 0, stream>>>(btab, btile);

    // 1. LN1 + window partition (fp32 -> bf16, window-ordered)
    ln_kernel<1, 0><<<25088, 256, 0, stream>>>(x, n1g, n1b, bufB);
    // 2. QKV GEMM -> bf16 (nB=6)
    gemm_kernel<0><<<6 * 784, 256, 0, stream>>>(bufB, wq, qkvb, bufA, nullptr,
                                                nullptr, nullptr, 768, 256, 6);
    // 3. MFMA window attention -> bf16 (window-ordered)
    attn_kernel<<<dim3(2048, 8), 64, 0, stream>>>(bufA, btile, bufB);
    // 4. proj GEMM + window reverse + residual -> x1 (bf16, spatial) (nB=2)
    gemm_kernel<2><<<2 * 784, 256, 0, stream>>>(bufB, wp, projb, x1, nullptr,
                                                x, nullptr, 256, 256, 2);
    // 5. LN2 (bf16 -> bf16, spatial)
    ln_kernel<0, 1><<<25088, 256, 0, stream>>>(x1, n2g, n2b, bufB);
    // 6. FFN1 + tanh-GELU -> bf16 (nB=8)
    gemm_kernel<1><<<8 * 784, 256, 0, stream>>>(bufB, wf1, b1, bufA, nullptr,
                                                nullptr, nullptr, 1024, 256, 8);
    // 7. FFN2 + residual -> d_out (fp32) (nB=2)
    gemm_kernel<3><<<2 * 784, 256, 0, stream>>>(bufA, wf2, b2, nullptr, (float*)d_out,
                                                nullptr, x1, 256, 1024, 2);
}